// Round 1
// baseline (1121.729 us; speedup 1.0000x reference)
//
#include <hip/hip_runtime.h>

#define NUSERS 100000
#define NITEMS 50000
#define NNODES 150000
#define DIM    128
#define NEDGES 4800000

// -------- row_ptr from sorted COO rows: lower_bound per node --------
__global__ void build_rowptr(const int* __restrict__ rows,
                             int* __restrict__ rowptr,
                             int n_nodes, int n_edges) {
    int r = blockIdx.x * blockDim.x + threadIdx.x;
    if (r > n_nodes) return;
    int lo = 0, hi = n_edges;
    while (lo < hi) {
        int mid = (lo + hi) >> 1;
        if (rows[mid] < r) lo = mid + 1; else hi = mid;
    }
    rowptr[r] = lo;
}

// -------- init: h0 = concat(user,item); acc(=out) = same --------
__global__ void init_kernel(const float4* __restrict__ ue,
                            const float4* __restrict__ ie,
                            float4* __restrict__ h,
                            float4* __restrict__ acc,
                            int n_user4, int n_total4) {
    int i = blockIdx.x * blockDim.x + threadIdx.x;
    if (i >= n_total4) return;
    float4 v = (i < n_user4) ? ue[i] : ie[i - n_user4];
    h[i]   = v;
    acc[i] = v;
}

// -------- SpMM: one wave per destination row; lane owns 2 columns --------
// h_new[r] = sum_{e in row r} vals[e] * h[cols[e]]
// acc[r]   = (acc[r] + h_new[r]) * scale
__global__ __launch_bounds__(256)
void spmm_kernel(const float* __restrict__ h,
                 float* __restrict__ hn,
                 float* __restrict__ acc,
                 const int* __restrict__ cols,
                 const float* __restrict__ vals,
                 const int* __restrict__ rowptr,
                 float scale, int n_nodes) {
    int wave = (int)((blockIdx.x * blockDim.x + threadIdx.x) >> 6);
    int lane = threadIdx.x & 63;
    if (wave >= n_nodes) return;

    int lo = rowptr[wave];
    int hi = rowptr[wave + 1];

    float sx = 0.f, sy = 0.f;
    for (int base = lo; base < hi; base += 64) {
        int e = base + lane;
        int c = 0; float v = 0.f;
        if (e < hi) { c = cols[e]; v = vals[e]; }
        int cnt = min(64, hi - base);
        for (int j = 0; j < cnt; ++j) {
            int   cj = __shfl(c, j);
            float vj = __shfl(v, j);
            const float2 hr = *reinterpret_cast<const float2*>(
                h + (size_t)cj * DIM + lane * 2);
            sx += vj * hr.x;
            sy += vj * hr.y;
        }
    }

    size_t off = (size_t)wave * DIM + lane * 2;
    *reinterpret_cast<float2*>(hn + off) = make_float2(sx, sy);

    float2 a = *reinterpret_cast<const float2*>(acc + off);
    a.x = (a.x + sx) * scale;
    a.y = (a.y + sy) * scale;
    *reinterpret_cast<float2*>(acc + off) = a;
}

extern "C" void kernel_launch(void* const* d_in, const int* in_sizes, int n_in,
                              void* d_out, int out_size, void* d_ws, size_t ws_size,
                              hipStream_t stream) {
    const float* ue   = (const float*)d_in[0];
    const float* ie   = (const float*)d_in[1];
    const int*   rows = (const int*)  d_in[2];
    const int*   cols = (const int*)  d_in[3];
    const float* vals = (const float*)d_in[4];
    float* out = (float*)d_out;

    char* ws = (char*)d_ws;
    int* rowptr = (int*)ws;
    size_t off = (((size_t)(NNODES + 1) * sizeof(int)) + 255) & ~(size_t)255;
    float* h0 = (float*)(ws + off);
    float* h1 = (float*)(ws + off + (size_t)NNODES * DIM * sizeof(float));

    // 1. row_ptr
    build_rowptr<<<(NNODES + 1 + 255) / 256, 256, 0, stream>>>(
        rows, rowptr, NNODES, NEDGES);

    // 2. init h0 and acc(=out)
    {
        int n_user4  = NUSERS * DIM / 4;
        int n_total4 = NNODES * DIM / 4;
        init_kernel<<<(n_total4 + 255) / 256, 256, 0, stream>>>(
            (const float4*)ue, (const float4*)ie,
            (float4*)h0, (float4*)out, n_user4, n_total4);
    }

    // 3. three SpMM layers, ping-pong h0/h1; fold final /4 into last layer
    int waves_per_block = 256 / 64;
    int blocks = (NNODES + waves_per_block - 1) / waves_per_block;

    spmm_kernel<<<blocks, 256, 0, stream>>>(h0, h1, out, cols, vals, rowptr, 1.0f,  NNODES);
    spmm_kernel<<<blocks, 256, 0, stream>>>(h1, h0, out, cols, vals, rowptr, 1.0f,  NNODES);
    spmm_kernel<<<blocks, 256, 0, stream>>>(h0, h1, out, cols, vals, rowptr, 0.25f, NNODES);
}

// Round 2
// 876.209 us; speedup vs baseline: 1.2802x; 1.2802x over previous
//
#include <hip/hip_runtime.h>

#define NUSERS 100000
#define NITEMS 50000
#define NNODES 150000
#define DIM    128
#define NEDGES 4800000

typedef unsigned int uint32;

// pack two fp32 -> two bf16 (round-to-nearest-even) in one uint
__device__ inline uint32 pack_bf16(float a, float b) {
    uint32 ua = __float_as_uint(a);
    ua += ((ua >> 16) & 1u) + 0x7FFFu;
    uint32 ub = __float_as_uint(b);
    ub += ((ub >> 16) & 1u) + 0x7FFFu;
    return (ua >> 16) | (ub & 0xFFFF0000u);
}

// -------- row_ptr from sorted COO rows: lower_bound per node --------
__global__ void build_rowptr(const int* __restrict__ rows,
                             int* __restrict__ rowptr,
                             int n_nodes, int n_edges) {
    int r = blockIdx.x * blockDim.x + threadIdx.x;
    if (r > n_nodes) return;
    int lo = 0, hi = n_edges;
    while (lo < hi) {
        int mid = (lo + hi) >> 1;
        if (rows[mid] < r) lo = mid + 1; else hi = mid;
    }
    rowptr[r] = lo;
}

// -------- init: h0(bf16) = concat(user,item); acc(fp32,=out) = same --------
__global__ void init_kernel(const float4* __restrict__ ue,
                            const float4* __restrict__ ie,
                            uint2* __restrict__ h,      // 4 bf16 per uint2
                            float4* __restrict__ acc,
                            int n_user4, int n_total4) {
    int i = blockIdx.x * blockDim.x + threadIdx.x;
    if (i >= n_total4) return;
    float4 v = (i < n_user4) ? ue[i] : ie[i - n_user4];
    acc[i] = v;
    h[i] = make_uint2(pack_bf16(v.x, v.y), pack_bf16(v.z, v.w));
}

// -------- SpMM: one wave per destination row; lane owns 2 columns --------
// h_new[r] = sum_{e in row r} vals[e] * h[cols[e]]   (h gathered as bf16)
// acc[r]   = (acc[r] + h_new[r]) * scale             (fp32)
__global__ __launch_bounds__(256)
void spmm_kernel(const uint32* __restrict__ h,   // bf16x2 per uint, row stride 64
                 uint32* __restrict__ hn,
                 float* __restrict__ acc,
                 const int* __restrict__ cols,
                 const float* __restrict__ vals,
                 const int* __restrict__ rowptr,
                 float scale, int n_nodes) {
    int wave = (int)((blockIdx.x * blockDim.x + threadIdx.x) >> 6);
    int lane = threadIdx.x & 63;
    if (wave >= n_nodes) return;

    int lo = rowptr[wave];
    int hi = rowptr[wave + 1];

    float sx = 0.f, sy = 0.f;
    for (int base = lo; base < hi; base += 64) {
        int e = base + lane;
        int c = 0; float v = 0.f;
        if (e < hi) { c = cols[e]; v = vals[e]; }
        int cnt = min(64, hi - base);
        #pragma unroll 4
        for (int j = 0; j < cnt; ++j) {
            int   cj = __shfl(c, j);
            float vj = __shfl(v, j);
            uint32 u = h[cj * 64 + lane];
            float hx = __uint_as_float(u << 16);
            float hy = __uint_as_float(u & 0xFFFF0000u);
            sx += vj * hx;
            sy += vj * hy;
        }
    }

    uint32 off = (uint32)wave * 64u + (uint32)lane;
    hn[off] = pack_bf16(sx, sy);

    float2 a = *reinterpret_cast<const float2*>(acc + (size_t)off * 2);
    a.x = (a.x + sx) * scale;
    a.y = (a.y + sy) * scale;
    *reinterpret_cast<float2*>(acc + (size_t)off * 2) = a;
}

extern "C" void kernel_launch(void* const* d_in, const int* in_sizes, int n_in,
                              void* d_out, int out_size, void* d_ws, size_t ws_size,
                              hipStream_t stream) {
    const float* ue   = (const float*)d_in[0];
    const float* ie   = (const float*)d_in[1];
    const int*   rows = (const int*)  d_in[2];
    const int*   cols = (const int*)  d_in[3];
    const float* vals = (const float*)d_in[4];
    float* out = (float*)d_out;

    char* ws = (char*)d_ws;
    int* rowptr = (int*)ws;
    size_t off = (((size_t)(NNODES + 1) * sizeof(int)) + 255) & ~(size_t)255;
    uint32* h0 = (uint32*)(ws + off);
    uint32* h1 = (uint32*)(ws + off + (size_t)NNODES * 64 * sizeof(uint32));

    // 1. row_ptr
    build_rowptr<<<(NNODES + 1 + 255) / 256, 256, 0, stream>>>(
        rows, rowptr, NNODES, NEDGES);

    // 2. init h0 (bf16) and acc(=out, fp32)
    {
        int n_user4  = NUSERS * DIM / 4;
        int n_total4 = NNODES * DIM / 4;
        init_kernel<<<(n_total4 + 255) / 256, 256, 0, stream>>>(
            (const float4*)ue, (const float4*)ie,
            (uint2*)h0, (float4*)out, n_user4, n_total4);
    }

    // 3. three SpMM layers, ping-pong h0/h1; fold final /4 into last layer
    int waves_per_block = 256 / 64;
    int blocks = (NNODES + waves_per_block - 1) / waves_per_block;

    spmm_kernel<<<blocks, 256, 0, stream>>>(h0, h1, out, cols, vals, rowptr, 1.0f,  NNODES);
    spmm_kernel<<<blocks, 256, 0, stream>>>(h1, h0, out, cols, vals, rowptr, 1.0f,  NNODES);
    spmm_kernel<<<blocks, 256, 0, stream>>>(h0, h1, out, cols, vals, rowptr, 0.25f, NNODES);
}

// Round 3
// 607.040 us; speedup vs baseline: 1.8479x; 1.4434x over previous
//
#include <hip/hip_runtime.h>

#define NUSERS 100000
#define NITEMS 50000
#define NNODES 150000
#define DIM    128
#define NEDGES 4800000
#define G 16

typedef unsigned int uint32;

// pack two fp32 -> two bf16 (round-to-nearest-even) in one uint
__device__ inline uint32 pack_bf16(float a, float b) {
    uint32 ua = __float_as_uint(a);
    ua += ((ua >> 16) & 1u) + 0x7FFFu;
    uint32 ub = __float_as_uint(b);
    ub += ((ub >> 16) & 1u) + 0x7FFFu;
    return (ua >> 16) | (ub & 0xFFFF0000u);
}

// -------- row_ptr from sorted COO rows: lower_bound per node --------
__global__ void build_rowptr(const int* __restrict__ rows,
                             int* __restrict__ rowptr,
                             int n_nodes, int n_edges) {
    int r = blockIdx.x * blockDim.x + threadIdx.x;
    if (r > n_nodes) return;
    int lo = 0, hi = n_edges;
    while (lo < hi) {
        int mid = (lo + hi) >> 1;
        if (rows[mid] < r) lo = mid + 1; else hi = mid;
    }
    rowptr[r] = lo;
}

// -------- init: h0(bf16) = concat(user,item); acc(fp32,=out) = same --------
__global__ void init_kernel(const float4* __restrict__ ue,
                            const float4* __restrict__ ie,
                            uint2* __restrict__ h,      // 4 bf16 per uint2
                            float4* __restrict__ acc,
                            int n_user4, int n_total4) {
    int i = blockIdx.x * blockDim.x + threadIdx.x;
    if (i >= n_total4) return;
    float4 v = (i < n_user4) ? ue[i] : ie[i - n_user4];
    acc[i] = v;
    h[i] = make_uint2(pack_bf16(v.x, v.y), pack_bf16(v.z, v.w));
}

// -------- SpMM: one wave per row; software-pipelined gathers --------
// h_new[r] = sum_{e in row r} vals[e] * h[cols[e]]   (h gathered as bf16)
// acc[r]   = (acc[r] + h_new[r]) * scale             (fp32)
__global__ __launch_bounds__(256)
void spmm_kernel(const uint32* __restrict__ h,   // bf16x2 per uint, row stride 64
                 uint32* __restrict__ hn,
                 float* __restrict__ acc,
                 const int* __restrict__ cols,
                 const float* __restrict__ vals,
                 const int* __restrict__ rowptr,
                 float scale, int n_nodes) {
    int wave = (int)((blockIdx.x * blockDim.x + threadIdx.x) >> 6);
    int lane = threadIdx.x & 63;
    if (wave >= n_nodes) return;

    int lo = rowptr[wave];
    int hi = rowptr[wave + 1];

    float sx = 0.f, sy = 0.f;

    for (int base = lo; base < hi; base += 64) {
        int e = base + lane;
        int c = 0; float v = 0.f;
        if (e < hi) { c = cols[e]; v = vals[e]; }
        int cnt = min(64, hi - base);
        int ng = (cnt + G - 1) / G;   // groups of 16 edges

        uint32 bufA[G], bufB[G];

        // issue 16 gathers for group g into buf (indices compile-time static)
        #define LOADG(buf, g) do {                                        \
            _Pragma("unroll")                                             \
            for (int j = 0; j < G; ++j) {                                 \
                int cj = __shfl(c, (g) * G + j);                          \
                (buf)[j] = h[(uint32)cj * 64u + (uint32)lane];            \
            } } while (0)

        // consume group g from buf (vj==0 for tail edges -> fma no-op)
        #define CONSUME(buf, g) do {                                      \
            _Pragma("unroll")                                             \
            for (int j = 0; j < G; ++j) {                                 \
                float vj = __shfl(v, (g) * G + j);                        \
                uint32 u = (buf)[j];                                      \
                sx += vj * __uint_as_float(u << 16);                      \
                sy += vj * __uint_as_float(u & 0xFFFF0000u);              \
            } } while (0)

        LOADG(bufA, 0);
        for (int gp = 0; gp < ng; gp += 2) {
            if (gp + 1 < ng) LOADG(bufB, gp + 1);
            CONSUME(bufA, gp);
            if (gp + 1 < ng) {
                if (gp + 2 < ng) LOADG(bufA, gp + 2);
                CONSUME(bufB, gp + 1);
            }
        }
        #undef LOADG
        #undef CONSUME
    }

    uint32 off = (uint32)wave * 64u + (uint32)lane;
    hn[off] = pack_bf16(sx, sy);

    float2 a = *reinterpret_cast<const float2*>(acc + (size_t)off * 2);
    a.x = (a.x + sx) * scale;
    a.y = (a.y + sy) * scale;
    *reinterpret_cast<float2*>(acc + (size_t)off * 2) = a;
}

extern "C" void kernel_launch(void* const* d_in, const int* in_sizes, int n_in,
                              void* d_out, int out_size, void* d_ws, size_t ws_size,
                              hipStream_t stream) {
    const float* ue   = (const float*)d_in[0];
    const float* ie   = (const float*)d_in[1];
    const int*   rows = (const int*)  d_in[2];
    const int*   cols = (const int*)  d_in[3];
    const float* vals = (const float*)d_in[4];
    float* out = (float*)d_out;

    char* ws = (char*)d_ws;
    int* rowptr = (int*)ws;
    size_t off = (((size_t)(NNODES + 1) * sizeof(int)) + 255) & ~(size_t)255;
    uint32* h0 = (uint32*)(ws + off);
    uint32* h1 = (uint32*)(ws + off + (size_t)NNODES * 64 * sizeof(uint32));

    // 1. row_ptr
    build_rowptr<<<(NNODES + 1 + 255) / 256, 256, 0, stream>>>(
        rows, rowptr, NNODES, NEDGES);

    // 2. init h0 (bf16) and acc(=out, fp32)
    {
        int n_user4  = NUSERS * DIM / 4;
        int n_total4 = NNODES * DIM / 4;
        init_kernel<<<(n_total4 + 255) / 256, 256, 0, stream>>>(
            (const float4*)ue, (const float4*)ie,
            (uint2*)h0, (float4*)out, n_user4, n_total4);
    }

    // 3. three SpMM layers, ping-pong h0/h1; fold final /4 into last layer
    int waves_per_block = 256 / 64;
    int blocks = (NNODES + waves_per_block - 1) / waves_per_block;

    spmm_kernel<<<blocks, 256, 0, stream>>>(h0, h1, out, cols, vals, rowptr, 1.0f,  NNODES);
    spmm_kernel<<<blocks, 256, 0, stream>>>(h1, h0, out, cols, vals, rowptr, 1.0f,  NNODES);
    spmm_kernel<<<blocks, 256, 0, stream>>>(h0, h1, out, cols, vals, rowptr, 0.25f, NNODES);
}

// Round 4
// 592.249 us; speedup vs baseline: 1.8940x; 1.0250x over previous
//
#include <hip/hip_runtime.h>

#define NUSERS 100000
#define NITEMS 50000
#define NNODES 150000
#define DIM    128
#define NEDGES 4800000

typedef unsigned int uint32;

// pack two fp32 -> two bf16 (round-to-nearest-even) in one uint
__device__ inline uint32 pack_bf16(float a, float b) {
    uint32 ua = __float_as_uint(a);
    ua += ((ua >> 16) & 1u) + 0x7FFFu;
    uint32 ub = __float_as_uint(b);
    ub += ((ub >> 16) & 1u) + 0x7FFFu;
    return (ua >> 16) | (ub & 0xFFFF0000u);
}

// -------- row_ptr from sorted COO rows: lower_bound per node --------
__global__ void build_rowptr(const int* __restrict__ rows,
                             int* __restrict__ rowptr,
                             int n_nodes, int n_edges) {
    int r = blockIdx.x * blockDim.x + threadIdx.x;
    if (r > n_nodes) return;
    int lo = 0, hi = n_edges;
    while (lo < hi) {
        int mid = (lo + hi) >> 1;
        if (rows[mid] < r) lo = mid + 1; else hi = mid;
    }
    rowptr[r] = lo;
}

// -------- init: h0(bf16) = concat(user,item); acc(fp32,=out) = same --------
__global__ void init_kernel(const float4* __restrict__ ue,
                            const float4* __restrict__ ie,
                            uint2* __restrict__ h,      // 4 bf16 per uint2
                            float4* __restrict__ acc,
                            int n_user4, int n_total4) {
    int i = blockIdx.x * blockDim.x + threadIdx.x;
    if (i >= n_total4) return;
    float4 v = (i < n_user4) ? ue[i] : ie[i - n_user4];
    acc[i] = v;
    h[i] = make_uint2(pack_bf16(v.x, v.y), pack_bf16(v.z, v.w));
}

// Straight-line S-slot row segment: scalar (wave-uniform) cols/vals loads,
// all S gathers issued before consumption. Tail slots clamp to hi-1 with
// val=0 (harmless re-gather of a hot line).
template<int S>
__device__ __forceinline__ void row_fixed(const uint32* __restrict__ h,
                                          const int* __restrict__ cols,
                                          const float* __restrict__ vals,
                                          int lo, int hi, int lane,
                                          float& sx, float& sy) {
    int   sc[S];
    float sv[S];
    uint32 buf[S];
    #pragma unroll
    for (int j = 0; j < S; ++j) {
        int e = lo + j;                       // wave-uniform
        int idx = e < hi ? e : hi - 1;        // uniform select -> s_cselect
        sc[j] = cols[idx];                    // s_load (merged)
        sv[j] = e < hi ? vals[idx] : 0.f;     // s_load + s_cselect
    }
    #pragma unroll
    for (int j = 0; j < S; ++j)
        buf[j] = h[(uint32)sc[j] * 64u + (uint32)lane];
    #pragma unroll
    for (int j = 0; j < S; ++j) {
        uint32 u = buf[j];
        sx += sv[j] * __uint_as_float(u << 16);
        sy += sv[j] * __uint_as_float(u & 0xFFFF0000u);
    }
}

// -------- SpMM: one wave per row --------
// h_new[r] = sum_{e in row r} vals[e] * h[cols[e]]   (h gathered as bf16)
// acc[r]   = (acc[r] + h_new[r]) * scale             (fp32)
__global__ __launch_bounds__(256)
void spmm_kernel(const uint32* __restrict__ h,   // bf16x2 per uint, row stride 64
                 uint32* __restrict__ hn,
                 float* __restrict__ acc,
                 const int* __restrict__ cols,
                 const float* __restrict__ vals,
                 const int* __restrict__ rowptr,
                 float scale, int n_nodes) {
    int wave = (int)((blockIdx.x * blockDim.x + threadIdx.x) >> 6);
    int lane = threadIdx.x & 63;
    if (wave >= n_nodes) return;

    int lo = __builtin_amdgcn_readfirstlane(rowptr[wave]);
    int hi = __builtin_amdgcn_readfirstlane(rowptr[wave + 1]);
    int len = hi - lo;

    float sx = 0.f, sy = 0.f;
    if (len > 0) {
        if      (len <= 16) row_fixed<16>(h, cols, vals, lo, hi, lane, sx, sy);
        else if (len <= 32) row_fixed<32>(h, cols, vals, lo, hi, lane, sx, sy);
        else if (len <= 48) row_fixed<48>(h, cols, vals, lo, hi, lane, sx, sy);
        else if (len <= 64) row_fixed<64>(h, cols, vals, lo, hi, lane, sx, sy);
        else {
            for (int b = lo; b < hi; b += 64)
                row_fixed<64>(h, cols, vals, b, hi, lane, sx, sy);
        }
    }

    uint32 off = (uint32)wave * 64u + (uint32)lane;
    hn[off] = pack_bf16(sx, sy);

    float2 a = *reinterpret_cast<const float2*>(acc + (size_t)off * 2);
    a.x = (a.x + sx) * scale;
    a.y = (a.y + sy) * scale;
    *reinterpret_cast<float2*>(acc + (size_t)off * 2) = a;
}

extern "C" void kernel_launch(void* const* d_in, const int* in_sizes, int n_in,
                              void* d_out, int out_size, void* d_ws, size_t ws_size,
                              hipStream_t stream) {
    const float* ue   = (const float*)d_in[0];
    const float* ie   = (const float*)d_in[1];
    const int*   rows = (const int*)  d_in[2];
    const int*   cols = (const int*)  d_in[3];
    const float* vals = (const float*)d_in[4];
    float* out = (float*)d_out;

    char* ws = (char*)d_ws;
    int* rowptr = (int*)ws;
    size_t off = (((size_t)(NNODES + 1) * sizeof(int)) + 255) & ~(size_t)255;
    uint32* h0 = (uint32*)(ws + off);
    uint32* h1 = (uint32*)(ws + off + (size_t)NNODES * 64 * sizeof(uint32));

    // 1. row_ptr
    build_rowptr<<<(NNODES + 1 + 255) / 256, 256, 0, stream>>>(
        rows, rowptr, NNODES, NEDGES);

    // 2. init h0 (bf16) and acc(=out, fp32)
    {
        int n_user4  = NUSERS * DIM / 4;
        int n_total4 = NNODES * DIM / 4;
        init_kernel<<<(n_total4 + 255) / 256, 256, 0, stream>>>(
            (const float4*)ue, (const float4*)ie,
            (uint2*)h0, (float4*)out, n_user4, n_total4);
    }

    // 3. three SpMM layers, ping-pong h0/h1; fold final /4 into last layer
    int waves_per_block = 256 / 64;
    int blocks = (NNODES + waves_per_block - 1) / waves_per_block;

    spmm_kernel<<<blocks, 256, 0, stream>>>(h0, h1, out, cols, vals, rowptr, 1.0f,  NNODES);
    spmm_kernel<<<blocks, 256, 0, stream>>>(h1, h0, out, cols, vals, rowptr, 1.0f,  NNODES);
    spmm_kernel<<<blocks, 256, 0, stream>>>(h0, h1, out, cols, vals, rowptr, 0.25f, NNODES);
}

// Round 5
// 560.938 us; speedup vs baseline: 1.9997x; 1.0558x over previous
//
#include <hip/hip_runtime.h>

#define NUSERS 100000
#define NITEMS 50000
#define NNODES 150000
#define DIM    128
#define NEDGES 4800000

typedef unsigned int uint32;

// pack two fp32 -> two bf16 (round-to-nearest-even) in one uint
__device__ inline uint32 pack_bf16(float a, float b) {
    uint32 ua = __float_as_uint(a);
    ua += ((ua >> 16) & 1u) + 0x7FFFu;
    uint32 ub = __float_as_uint(b);
    ub += ((ub >> 16) & 1u) + 0x7FFFu;
    return (ua >> 16) | (ub & 0xFFFF0000u);
}

// -------- row_ptr from sorted COO rows: lower_bound per node --------
__global__ void build_rowptr(const int* __restrict__ rows,
                             int* __restrict__ rowptr,
                             int n_nodes, int n_edges) {
    int r = blockIdx.x * blockDim.x + threadIdx.x;
    if (r > n_nodes) return;
    int lo = 0, hi = n_edges;
    while (lo < hi) {
        int mid = (lo + hi) >> 1;
        if (rows[mid] < r) lo = mid + 1; else hi = mid;
    }
    rowptr[r] = lo;
}

// -------- init: h0(bf16) = concat(user,item) --------
__global__ void init_kernel(const float4* __restrict__ ue,
                            const float4* __restrict__ ie,
                            uint2* __restrict__ h,      // 4 bf16 per uint2
                            int n_user4, int n_total4) {
    int i = blockIdx.x * blockDim.x + threadIdx.x;
    if (i >= n_total4) return;
    float4 v = (i < n_user4) ? ue[i] : ie[i - n_user4];
    h[i] = make_uint2(pack_bf16(v.x, v.y), pack_bf16(v.z, v.w));
}

// Straight-line S-slot row segment: scalar (wave-uniform) cols/vals loads,
// all S gathers issued before consumption. Tail slots clamp to hi-1 with
// val=0 (harmless re-gather of a hot line).
template<int S>
__device__ __forceinline__ void row_fixed(const uint32* __restrict__ h,
                                          const int* __restrict__ cols,
                                          const float* __restrict__ vals,
                                          int lo, int hi, int lane,
                                          float& sx, float& sy) {
    int   sc[S];
    float sv[S];
    uint32 buf[S];
    #pragma unroll
    for (int j = 0; j < S; ++j) {
        int e = lo + j;                       // wave-uniform
        int idx = e < hi ? e : hi - 1;        // uniform select -> s_cselect
        sc[j] = cols[idx];                    // s_load (merged)
        sv[j] = e < hi ? vals[idx] : 0.f;     // s_load + s_cselect
    }
    #pragma unroll
    for (int j = 0; j < S; ++j)
        buf[j] = h[(uint32)sc[j] * 64u + (uint32)lane];
    #pragma unroll
    for (int j = 0; j < S; ++j) {
        uint32 u = buf[j];
        sx += sv[j] * __uint_as_float(u << 16);
        sy += sv[j] * __uint_as_float(u & 0xFFFF0000u);
    }
}

__device__ __forceinline__ void row_dispatch(const uint32* __restrict__ h,
                                             const int* __restrict__ cols,
                                             const float* __restrict__ vals,
                                             int lo, int hi, int lane,
                                             float& sx, float& sy) {
    int len = hi - lo;
    if (len <= 0) return;
    if      (len <= 16) row_fixed<16>(h, cols, vals, lo, hi, lane, sx, sy);
    else if (len <= 32) row_fixed<32>(h, cols, vals, lo, hi, lane, sx, sy);
    else if (len <= 48) row_fixed<48>(h, cols, vals, lo, hi, lane, sx, sy);
    else if (len <= 64) row_fixed<64>(h, cols, vals, lo, hi, lane, sx, sy);
    else {
        for (int b = lo; b < hi; b += 64)
            row_fixed<64>(h, cols, vals, b, hi, lane, sx, sy);
    }
}

// -------- mid layers: h_new[r] = sum vals*h[cols], bf16 store only --------
__global__ __launch_bounds__(256)
void spmm_mid(const uint32* __restrict__ h,
              uint32* __restrict__ hn,
              const int* __restrict__ cols,
              const float* __restrict__ vals,
              const int* __restrict__ rowptr,
              int n_nodes) {
    int wave = (int)((blockIdx.x * blockDim.x + threadIdx.x) >> 6);
    int lane = threadIdx.x & 63;
    if (wave >= n_nodes) return;

    int lo = __builtin_amdgcn_readfirstlane(rowptr[wave]);
    int hi = __builtin_amdgcn_readfirstlane(rowptr[wave + 1]);

    float sx = 0.f, sy = 0.f;
    row_dispatch(h, cols, vals, lo, hi, lane, sx, sy);

    hn[(uint32)wave * 64u + (uint32)lane] = pack_bf16(sx, sy);
}

// -------- last layer fused with final combine --------
// out[r] = (h0[r] + h1[r] + h2[r] + h3[r]) * 0.25, h3 computed in regs
__global__ __launch_bounds__(256)
void spmm_last(const uint32* __restrict__ h2,   // gather source (layer-2 output)
               const uint32* __restrict__ h0,
               const uint32* __restrict__ h1,
               float* __restrict__ out,
               const int* __restrict__ cols,
               const float* __restrict__ vals,
               const int* __restrict__ rowptr,
               int n_nodes) {
    int wave = (int)((blockIdx.x * blockDim.x + threadIdx.x) >> 6);
    int lane = threadIdx.x & 63;
    if (wave >= n_nodes) return;

    int lo = __builtin_amdgcn_readfirstlane(rowptr[wave]);
    int hi = __builtin_amdgcn_readfirstlane(rowptr[wave + 1]);

    float sx = 0.f, sy = 0.f;                  // h3 row (fp32)
    row_dispatch(h2, cols, vals, lo, hi, lane, sx, sy);

    uint32 off = (uint32)wave * 64u + (uint32)lane;
    uint32 u0 = h0[off], u1 = h1[off], u2 = h2[off];

    float ax = __uint_as_float(u0 << 16) + __uint_as_float(u1 << 16)
             + __uint_as_float(u2 << 16) + sx;
    float ay = __uint_as_float(u0 & 0xFFFF0000u) + __uint_as_float(u1 & 0xFFFF0000u)
             + __uint_as_float(u2 & 0xFFFF0000u) + sy;

    *reinterpret_cast<float2*>(out + (size_t)off * 2) =
        make_float2(ax * 0.25f, ay * 0.25f);
}

extern "C" void kernel_launch(void* const* d_in, const int* in_sizes, int n_in,
                              void* d_out, int out_size, void* d_ws, size_t ws_size,
                              hipStream_t stream) {
    const float* ue   = (const float*)d_in[0];
    const float* ie   = (const float*)d_in[1];
    const int*   rows = (const int*)  d_in[2];
    const int*   cols = (const int*)  d_in[3];
    const float* vals = (const float*)d_in[4];
    float* out = (float*)d_out;

    char* ws = (char*)d_ws;
    int* rowptr = (int*)ws;
    size_t off = (((size_t)(NNODES + 1) * sizeof(int)) + 255) & ~(size_t)255;
    size_t hbytes = (size_t)NNODES * 64 * sizeof(uint32);
    uint32* h0 = (uint32*)(ws + off);
    uint32* h1 = (uint32*)(ws + off + hbytes);
    uint32* h2 = (uint32*)(ws + off + 2 * hbytes);

    // 1. row_ptr
    build_rowptr<<<(NNODES + 1 + 255) / 256, 256, 0, stream>>>(
        rows, rowptr, NNODES, NEDGES);

    // 2. init h0 (bf16)
    {
        int n_user4  = NUSERS * DIM / 4;
        int n_total4 = NNODES * DIM / 4;
        init_kernel<<<(n_total4 + 255) / 256, 256, 0, stream>>>(
            (const float4*)ue, (const float4*)ie, (uint2*)h0,
            n_user4, n_total4);
    }

    // 3. layers
    int waves_per_block = 256 / 64;
    int blocks = (NNODES + waves_per_block - 1) / waves_per_block;

    spmm_mid <<<blocks, 256, 0, stream>>>(h0, h1, cols, vals, rowptr, NNODES);
    spmm_mid <<<blocks, 256, 0, stream>>>(h1, h2, cols, vals, rowptr, NNODES);
    spmm_last<<<blocks, 256, 0, stream>>>(h2, h0, h1, out, cols, vals, rowptr, NNODES);
}